// Round 1
// 2435.266 us; speedup vs baseline: 1.1729x; 1.1729x over previous
//
#include <hip/hip_runtime.h>
#include <math.h>

#define NB    4096   // batch N
#define FEAT  1024
#define MSUP  512    // SUPPORT
#define G4    4096   // 4*FEAT
#define NWAYS 20     // n_ways fixed to 20 per setup_inputs()

typedef _Float16 f16;
typedef f16 f16x8 __attribute__((ext_vector_type(8)));
typedef f16 f16x4 __attribute__((ext_vector_type(4)));
typedef float f32x4 __attribute__((ext_vector_type(4)));
typedef unsigned int u32;
#define GLOBAL_AS __attribute__((address_space(1)))
#define LDS_AS    __attribute__((address_space(3)))

__device__ __forceinline__ void load_lds16(const void* g, void* l) {
    __builtin_amdgcn_global_load_lds((const GLOBAL_AS u32*)g, (LDS_AS u32*)l, 16, 0, 0);
}

__device__ __forceinline__ float sigm(float x) { return 1.f / (1.f + __expf(-x)); }

// ---------------- plain f16 MFMA NT GEMM (R2-proven core) ----------------
// C[m,n] = sum_k A[m,k]*B[n,k]; up to three (A,B,K) pairs; optional bias.
template<int BM, int BN, int WROWS, int WCOLS, bool OUTF16, bool HASBIAS>
__global__ __launch_bounds__(256) void mfma_nt(
    void* __restrict__ Cv, int ldc,
    const f16* __restrict__ A1, int lda1, const f16* __restrict__ B1, int ldb1, int K1,
    const f16* __restrict__ A2, int lda2, const f16* __restrict__ B2, int ldb2, int K2,
    const f16* __restrict__ A3, int lda3, const f16* __restrict__ B3, int ldb3, int K3,
    const float* __restrict__ bias)
{
    constexpr int BK = 32;
    constexpr int WM = BM / WROWS, WN = BN / WCOLS;
    constexpr int FM = WM / 16,   FN = WN / 16;
    __shared__ f16 As[BM][BK];
    __shared__ f16 Bs[BN][BK];
    const int tid  = threadIdx.x;
    const int lane = tid & 63;
    const int wrow = (tid >> 6) % WROWS, wcol = (tid >> 6) / WROWS;
    const int bm = blockIdx.y * BM, bn = blockIdx.x * BN;
    const int lr = lane & 15, lq = lane >> 4;

    f32x4 acc[FM][FN] = {};

    #pragma unroll
    for (int pass = 0; pass < 3; ++pass) {
        const f16* A = pass == 0 ? A1 : (pass == 1 ? A2 : A3);
        const f16* B = pass == 0 ? B1 : (pass == 1 ? B2 : B3);
        const int lda = pass == 0 ? lda1 : (pass == 1 ? lda2 : lda3);
        const int ldb = pass == 0 ? ldb1 : (pass == 1 ? ldb2 : ldb3);
        const int K   = pass == 0 ? K1  : (pass == 1 ? K2  : K3);
        if (!A) break;
        #pragma unroll 1
        for (int k0 = 0; k0 < K; k0 += BK) {
            __syncthreads();
            #pragma unroll
            for (int t = 0; t < (BM * 4) / 256; ++t) {
                int c = t * 256 + tid;
                load_lds16(A + (size_t)(bm + (c >> 2)) * lda + k0 + (c & 3) * 8,
                           &As[0][0] + ((size_t)t * 256 + (tid & 192)) * 8);
            }
            #pragma unroll
            for (int t = 0; t < (BN * 4) / 256; ++t) {
                int c = t * 256 + tid;
                load_lds16(B + (size_t)(bn + (c >> 2)) * ldb + k0 + (c & 3) * 8,
                           &Bs[0][0] + ((size_t)t * 256 + (tid & 192)) * 8);
            }
            __syncthreads();
            f16x8 af[FM], bf[FN];
            #pragma unroll
            for (int i = 0; i < FM; ++i)
                af[i] = *(const f16x8*)&As[wrow * WM + i * 16 + lr][lq * 8];
            #pragma unroll
            for (int j = 0; j < FN; ++j)
                bf[j] = *(const f16x8*)&Bs[wcol * WN + j * 16 + lr][lq * 8];
            #pragma unroll
            for (int i = 0; i < FM; ++i)
                #pragma unroll
                for (int j = 0; j < FN; ++j)
                    acc[i][j] = __builtin_amdgcn_mfma_f32_16x16x32_f16(af[i], bf[j], acc[i][j], 0, 0, 0);
        }
    }

    #pragma unroll
    for (int i = 0; i < FM; ++i) {
        #pragma unroll
        for (int j = 0; j < FN; ++j) {
            const int col  = bn + wcol * WN + j * 16 + lr;
            const int row0 = bm + wrow * WM + i * 16 + lq * 4;
            float badd = HASBIAS ? bias[col] : 0.f;
            #pragma unroll
            for (int r = 0; r < 4; ++r) {
                size_t off = (size_t)(row0 + r) * ldc + col;
                float v = acc[i][j][r] + badd;
                if (OUTF16) ((f16*)Cv)[off] = (f16)v;
                else        ((float*)Cv)[off] = v;
            }
        }
    }
}

// ------------- fused gates GEMM + LSTM cell — 256x256 tile, 8-phase-class -------------
// Single unified K=2048 pass: gates = pre + A(k)·Wcat^T where
//   A cols [0,512)=a, [512,1024)=a (lo half), [1024,2048)=h
//   Wcat cols       = [Wr_hi | Wr_lo | Whh]   (built once in setup)
// Schedule (T2+T3+T4+T5+T1 from the measured catalog):
//  - 512 threads = 8 waves (2M x 4N), per-wave 128x64 output, BK=64, LDS 2x64KB dbuf.
//  - per K-tile: 4 phases, each {2 global_load_lds for tile t+1 -> other buffer,
//    quadrant ds_reads, raw barrier, 16 MFMA under setprio(1), raw barrier}.
//  - counted s_waitcnt vmcnt(2) ONCE per tile (drains exactly tile t's 8 loads/wave,
//    keeps tile t+1's prefetch in flight); vmcnt(0) only on the last tile.
//  - LDS XOR swizzle byte^=((row&7)<<4) applied on the READ side; inverse applied to
//    the GLOBAL source address (global_load_lds dest must stay linear — rule #21).
// Sync invariants (why this is race-free):
//  (1) every wave executes vmcnt(2/0) THEN an asm("s_barrier":::"memory") before any
//      ds_read of tile t => all 8 waves' staging of tile t has landed.
//  (2) each wave's ds_reads of a tile are lgkm-drained before its phase-4 MFMAs
//      (compiler-tracked deps), hence before the iteration-end barrier => next
//      iteration's staging into that buffer is WAR-safe.
//  (3) correctness-critical barriers are inline-asm with "memory" clobber
//      (raw __builtin_amdgcn_s_barrier is IntrNoMem; loads may be hoisted across it).
__global__ __launch_bounds__(512, 2) void gates_8p(
    const f16* __restrict__ a,     // [NB][MSUP]
    const f16* __restrict__ h,     // [NB][FEAT]
    const f16* __restrict__ Wcat,  // [G4][2048] permuted rows
    const f16* __restrict__ pre,   // [NB][G4] (permuted cols)
    const float* __restrict__ fin, // [NB][FEAT] f32
    float* __restrict__ cbuf,      // block-private c, f32 (R7: must stay f32)
    f16* __restrict__ hh,          // [NB][FEAT] f16 h_next
    float* __restrict__ hout,      // [NB][FEAT] f32 (writeH)
    int first, int writeH)
{
    extern __shared__ f16x8 smem8[];
    f16* smem = (f16*)smem8;        // [2 buffers][A:16384 f16 | B:16384 f16]
    const int tid  = threadIdx.x;
    const int lane = tid & 63;
    const int wid  = tid >> 6;
    const int wrow = wid >> 2, wcol = wid & 3;   // 2M x 4N waves
    const int lr = lane & 15, lq = lane >> 4;

    // T1: bijective XCD swizzle (256 blocks, 256%8==0): XCD x gets 2 row-panels.
    const int bidr = blockIdx.y * 16 + blockIdx.x;
    const int wg   = (bidr & 7) * 32 + (bidr >> 3);
    const int bm = (wg >> 4) * 256;   // batch rows
    const int bn = (wg & 15) * 256;   // gate cols

    f32x4 acc[8][4] = {};

    auto stage = [&](const f16* src, int ld, int rb, int ko, f16* lbase, int l) {
        int c = l * 512 + tid;           // 16B chunk id: row = c>>3, chunk = c&7
        int r = c >> 3;
        int x = (c & 7) ^ (r & 7);       // inverse (== forward, involution) swizzle
        load_lds16(src + (size_t)(rb + r) * ld + ko + (x << 3),
                   lbase + ((size_t)(l * 512 + (tid & 448))) * 8);
    };
    // swizzled fragment read: row stride 64 f16 (=128B), chunk ^= (row&7)
    #define RDF(BUF, RB, KK) \
        (*(const f16x8*)((BUF) + ((size_t)((RB) + lr) << 6) + ((((KK) << 2 | lq) ^ (lr & 7)) << 3)))

    // prologue: stage tile 0 -> buffer 0 (8 loads/wave)
    #pragma unroll
    for (int l = 0; l < 4; ++l) {
        stage(a,    MSUP, bm, 0, smem,         l);
        stage(Wcat, 2048, bn, 0, smem + 16384, l);
    }

    #pragma unroll 1
    for (int t = 0; t < 32; ++t) {
        f16* Ab = smem + (t & 1) * 32768;
        f16* Bb = Ab + 16384;
        f16* An = smem + ((t + 1) & 1) * 32768;
        f16* Bn = An + 16384;
        const int k1 = (t + 1) * 64;                 // k-offset of the tile we stage
        const f16* As2 = a; int lda2 = MSUP, ko2 = k1;
        if (k1 >= 1024)     { As2 = h; lda2 = FEAT; ko2 = k1 - 1024; }
        else if (k1 >= 512) { ko2 = k1 - 512; }
        const bool st = (t < 31);

        f16x8 af[4][2], bf[2][2], bg[2][2];

        // ---- phase 1 : stage l=0, validate tile t, Q(i0-3, j0-1) ----
        if (st) {
            stage(As2, lda2, bm, ko2, An, 0);
            stage(Wcat, 2048, bn, k1, Bn, 0);
            asm volatile("s_waitcnt vmcnt(2)" ::: "memory");
        } else {
            asm volatile("s_waitcnt vmcnt(0)" ::: "memory");
        }
        asm volatile("s_barrier" ::: "memory");      // tile t visible to all waves
        #pragma unroll
        for (int i = 0; i < 4; ++i)
            #pragma unroll
            for (int kk = 0; kk < 2; ++kk)
                af[i][kk] = RDF(Ab, wrow * 128 + i * 16, kk);
        #pragma unroll
        for (int j = 0; j < 2; ++j)
            #pragma unroll
            for (int kk = 0; kk < 2; ++kk)
                bf[j][kk] = RDF(Bb, wcol * 64 + j * 16, kk);
        __builtin_amdgcn_s_setprio(1);
        #pragma unroll
        for (int kk = 0; kk < 2; ++kk)
            #pragma unroll
            for (int i = 0; i < 4; ++i)
                #pragma unroll
                for (int j = 0; j < 2; ++j)
                    acc[i][j] = __builtin_amdgcn_mfma_f32_16x16x32_f16(af[i][kk], bf[j][kk], acc[i][j], 0, 0, 0);
        __builtin_amdgcn_s_setprio(0);
        __builtin_amdgcn_s_barrier();

        // ---- phase 2 : stage l=1, Q(i0-3, j2-3) ----
        if (st) { stage(As2, lda2, bm, ko2, An, 1); stage(Wcat, 2048, bn, k1, Bn, 1); }
        #pragma unroll
        for (int j = 0; j < 2; ++j)
            #pragma unroll
            for (int kk = 0; kk < 2; ++kk)
                bg[j][kk] = RDF(Bb, wcol * 64 + (j + 2) * 16, kk);
        __builtin_amdgcn_s_barrier();
        __builtin_amdgcn_s_setprio(1);
        #pragma unroll
        for (int kk = 0; kk < 2; ++kk)
            #pragma unroll
            for (int i = 0; i < 4; ++i)
                #pragma unroll
                for (int j = 0; j < 2; ++j)
                    acc[i][j + 2] = __builtin_amdgcn_mfma_f32_16x16x32_f16(af[i][kk], bg[j][kk], acc[i][j + 2], 0, 0, 0);
        __builtin_amdgcn_s_setprio(0);
        __builtin_amdgcn_s_barrier();

        // ---- phase 3 : stage l=2, Q(i4-7, j2-3) (af regs reused) ----
        if (st) { stage(As2, lda2, bm, ko2, An, 2); stage(Wcat, 2048, bn, k1, Bn, 2); }
        #pragma unroll
        for (int i = 0; i < 4; ++i)
            #pragma unroll
            for (int kk = 0; kk < 2; ++kk)
                af[i][kk] = RDF(Ab, wrow * 128 + (i + 4) * 16, kk);
        __builtin_amdgcn_s_barrier();
        __builtin_amdgcn_s_setprio(1);
        #pragma unroll
        for (int kk = 0; kk < 2; ++kk)
            #pragma unroll
            for (int i = 0; i < 4; ++i)
                #pragma unroll
                for (int j = 0; j < 2; ++j)
                    acc[i + 4][j + 2] = __builtin_amdgcn_mfma_f32_16x16x32_f16(af[i][kk], bg[j][kk], acc[i + 4][j + 2], 0, 0, 0);
        __builtin_amdgcn_s_setprio(0);
        __builtin_amdgcn_s_barrier();

        // ---- phase 4 : stage l=3, Q(i4-7, j0-1) (bf re-read: saves 16 VGPR) ----
        if (st) { stage(As2, lda2, bm, ko2, An, 3); stage(Wcat, 2048, bn, k1, Bn, 3); }
        #pragma unroll
        for (int j = 0; j < 2; ++j)
            #pragma unroll
            for (int kk = 0; kk < 2; ++kk)
                bf[j][kk] = RDF(Bb, wcol * 64 + j * 16, kk);
        __builtin_amdgcn_s_barrier();
        __builtin_amdgcn_s_setprio(1);
        #pragma unroll
        for (int kk = 0; kk < 2; ++kk)
            #pragma unroll
            for (int i = 0; i < 4; ++i)
                #pragma unroll
                for (int j = 0; j < 2; ++j)
                    acc[i + 4][j] = __builtin_amdgcn_mfma_f32_16x16x32_f16(af[i][kk], bf[j][kk], acc[i + 4][j], 0, 0, 0);
        __builtin_amdgcn_s_setprio(0);
        asm volatile("s_barrier" ::: "memory");      // iteration end: frees buf[t&1]
    }
    #undef RDF

    // ---- fused cell epilogue (quad-transpose per 16x16 fragment, as verified) ----
    const int q  = lane & 3;
    const int fk = (lane >> 2) & 3;
    #pragma unroll
    for (int i = 0; i < 8; ++i) {
        #pragma unroll
        for (int j = 0; j < 4; ++j) {
            const int cb   = bn + wcol * 64 + j * 16;
            const int row0 = bm + wrow * 128 + i * 16 + lq * 4;
            float x[4];
            #pragma unroll
            for (int r = 0; r < 4; ++r) x[r] = acc[i][j][r];
            float g4[4];
            #pragma unroll
            for (int k = 0; k < 4; ++k) {
                int srcq = (q + k) & 3;
                int src  = (lane & ~3) | srcq;
                g4[srcq] = __shfl(x[(q - k + 4) & 3], src, 64);
            }
            const int row  = row0 + q;
            const int feat = (cb >> 2) + fk;
            f16x4 p = *(const f16x4*)(pre + (size_t)row * G4 + cb + 4 * fk);
            const float i_ = sigm(g4[0] + (float)p[0]);
            const float f_ = sigm(g4[1] + (float)p[1]);
            const float g_ = tanhf(g4[2] + (float)p[2]);
            const float o_ = sigm(g4[3] + (float)p[3]);
            const size_t cid = ((size_t)(blockIdx.y * gridDim.x + blockIdx.x) * 32
                                + i * 4 + j) * 512 + tid;
            float cold = first ? 0.f : cbuf[cid];
            float cn = i_ * g_ + f_ * cold;
            cbuf[cid] = cn;                 // f32 — f16 here injects 2.4e-4/iter (R7 fail)
            float hn = o_ * tanhf(cn) + fin[(size_t)row * FEAT + feat];
            hh[(size_t)row * FEAT + feat] = (f16)hn;
            if (writeH) hout[(size_t)row * FEAT + feat] = hn;
        }
    }
}

// -------- softmax along contiguous rows; in f32 [rows][4096] -> out f16 --------
__global__ __launch_bounds__(256) void softmax_rows_kernel(
    const float* __restrict__ X, f16* __restrict__ Y)
{
    const int row = blockIdx.x;
    const float* x = X + (size_t)row * NB;
    f16* y = Y + (size_t)row * NB;
    const int tid = threadIdx.x;
    float v[16];
    float mx = -1e30f;
    #pragma unroll
    for (int i = 0; i < 16; ++i) { v[i] = x[tid + (i << 8)]; mx = fmaxf(mx, v[i]); }
    #pragma unroll
    for (int off = 32; off > 0; off >>= 1) mx = fmaxf(mx, __shfl_down(mx, off));
    __shared__ float sm[4];
    if ((tid & 63) == 0) sm[tid >> 6] = mx;
    __syncthreads();
    mx = fmaxf(fmaxf(sm[0], sm[1]), fmaxf(sm[2], sm[3]));
    float s = 0.f;
    #pragma unroll
    for (int i = 0; i < 16; ++i) { v[i] = __expf(v[i] - mx); s += v[i]; }
    #pragma unroll
    for (int off = 32; off > 0; off >>= 1) s += __shfl_down(s, off);
    __shared__ float ss[4];
    if ((tid & 63) == 0) ss[tid >> 6] = s;
    __syncthreads();
    s = ss[0] + ss[1] + ss[2] + ss[3];
    const float inv = 1.f / s;
    #pragma unroll
    for (int i = 0; i < 16; ++i) y[tid + (i << 8)] = (f16)(v[i] * inv);
}

// -------- transpose: f16 [R][C] -> f16 [C][R] --------
__global__ __launch_bounds__(256) void transpose_f16_kernel(
    const f16* __restrict__ in, f16* __restrict__ out, int R, int C)
{
    __shared__ f16 t[64][65];
    const int r0 = blockIdx.y * 64, c0 = blockIdx.x * 64;
    const int lr = threadIdx.x & 63, lw = threadIdx.x >> 6;
    #pragma unroll
    for (int i = 0; i < 16; ++i) {
        int rr = lw * 16 + i;
        t[rr][lr] = in[(size_t)(r0 + rr) * C + c0 + lr];
    }
    __syncthreads();
    #pragma unroll
    for (int i = 0; i < 16; ++i) {
        int cc = lw * 16 + i;
        out[(size_t)(c0 + cc) * R + r0 + lr] = t[lr][cc];
    }
}

// -------- f32 -> f16 convert --------
__global__ __launch_bounds__(256) void cvt_f16_kernel(
    const float* __restrict__ in, f16* __restrict__ out, int n)
{
    int idx = (blockIdx.x * 256 + threadIdx.x) * 4;
    if (idx < n) {
        float4 v = *(const float4*)(in + idx);
        f16x4 o = {(f16)v.x, (f16)v.y, (f16)v.z, (f16)v.w};
        *(f16x4*)(out + idx) = o;
    }
}

// -------- row-permuted f16 conversion with dst stride/offset:
// dst row 4*(j&1023)+(j>>10) = src row j; writes out[dst*ld_out + col_off + k] ----
__global__ __launch_bounds__(256) void cvt_perm_kernel(
    const float* __restrict__ in, f16* __restrict__ out, int ld_in, int ld_out, int col_off)
{
    int idx = (blockIdx.x * 256 + threadIdx.x) * 4;
    int j = idx / ld_in, k = idx % ld_in;
    int dst = 4 * (j & 1023) + (j >> 10);
    float4 v = *(const float4*)(in + idx);
    f16x4 o = {(f16)v.x, (f16)v.y, (f16)v.z, (f16)v.w};
    *(f16x4*)(out + (size_t)dst * ld_out + col_off + k) = o;
}

// -------- permuted combined bias: bias_p[4*(j&1023)+(j>>10)] = bih[j]+bhh[j] ----
__global__ __launch_bounds__(256) void bias_perm_kernel(
    const float* __restrict__ bih, const float* __restrict__ bhh, float* __restrict__ out)
{
    int j = blockIdx.x * 256 + threadIdx.x;
    out[4 * (j & 1023) + (j >> 10)] = bih[j] + bhh[j];
}

// -------- Wr32 [G4][512] f32 -> Wcat hi/lo halves: hi at col k, lo at col 512+k ----
__global__ __launch_bounds__(256) void split_wcat_kernel(
    const float* __restrict__ in, f16* __restrict__ out)
{
    int idx = (blockIdx.x * 256 + threadIdx.x) * 4;   // over G4*MSUP
    int g = idx >> 9, k = idx & 511;
    float4 v = *(const float4*)(in + idx);
    f16x4 hi = {(f16)v.x, (f16)v.y, (f16)v.z, (f16)v.w};
    f16x4 lo = {(f16)(v.x - (float)hi.x), (f16)(v.y - (float)hi.y),
                (f16)(v.z - (float)hi.z), (f16)(v.w - (float)hi.w)};
    *(f16x4*)(out + (size_t)g * 2048 + k) = hi;
    *(f16x4*)(out + (size_t)g * 2048 + 512 + k) = lo;
}

extern "C" void kernel_launch(void* const* d_in, const int* in_sizes, int n_in,
                              void* d_out, int out_size, void* d_ws, size_t ws_size,
                              hipStream_t stream) {
    const float* f   = (const float*)d_in[0];   // [NB, FEAT]
    const float* G   = (const float*)d_in[1];   // [MSUP, FEAT]
    const float* Wih = (const float*)d_in[2];   // [G4, 2*FEAT]
    const float* Whh = (const float*)d_in[3];   // [G4, FEAT]
    const float* bih = (const float*)d_in[4];   // [G4]
    const float* bhh = (const float*)d_in[5];   // [G4]
    float* h = (float*)d_out;                   // [NB, FEAT]

    char* W = (char*)d_ws;
    f16*   pre_h   = (f16*)(W);                          // 32 MB [NB][G4] (permuted cols)
    float* aT      = (float*)(W + (size_t)(32 << 20));   //  8 MB [MSUP][NB]
    f16*   aTh     = (f16*)(W + (size_t)(40 << 20));     //  4 MB [MSUP][NB]
    f16*   a_h     = (f16*)(W + (size_t)(44 << 20));     //  4 MB [NB][MSUP]
    float* cbuf    = (float*)(W + (size_t)(48 << 20));   // 16 MB block-private c (f32!)
    f16*   h0      = (f16*)(W + (size_t)(64 << 20));     //  8 MB [NB][FEAT] = f16(f)
    f16*   hA      = (f16*)(W + (size_t)(72 << 20));     //  8 MB h ping
    f16*   hB      = (f16*)(W + (size_t)(80 << 20));     //  8 MB h pong
    f16*   Wih_h   = (f16*)(W + (size_t)(88 << 20));     // 16 MB [G4][2F] (permuted rows)
    f16*   Wcat    = (f16*)(W + (size_t)(104 << 20));    // 16 MB [G4][2048] = [Wr_hi|Wr_lo|Whh]
    float* Wr32    = (float*)(W + (size_t)(120 << 20));  //  8 MB [G4][MSUP] (permuted rows)
    f16*   G_h     = (f16*)(W + (size_t)(128 << 20));    //  1 MB [MSUP][FEAT]
    float* bias_p  = (float*)(W + (size_t)(129 << 20));  // 16 KB

    const f16* NF = nullptr;
    const dim3 blk(256);

    hipFuncSetAttribute((const void*)gates_8p,
                        hipFuncAttributeMaxDynamicSharedMemorySize, 131072);

    // setup (every call — ws is re-poisoned)
    cvt_f16_kernel<<<(NB * FEAT) / 1024, blk, 0, stream>>>(f, h0, NB * FEAT);
    cvt_perm_kernel<<<(G4 * 2 * FEAT) / 1024, blk, 0, stream>>>(Wih, Wih_h, 2 * FEAT, 2 * FEAT, 0);
    cvt_perm_kernel<<<(G4 * FEAT) / 1024, blk, 0, stream>>>(Whh, Wcat, FEAT, 2048, 1024);
    cvt_f16_kernel<<<(MSUP * FEAT) / 1024, blk, 0, stream>>>(G, G_h, MSUP * FEAT);
    bias_perm_kernel<<<G4 / 256, blk, 0, stream>>>(bih, bhh, bias_p);

    // pre = f @ W_f^T + biases (permuted cols; constant across iterations)
    mfma_nt<128, 128, 2, 2, true, true><<<dim3(G4 / 128, NB / 128), blk, 0, stream>>>(
        pre_h, G4,
        h0, FEAT, Wih_h, 2 * FEAT, FEAT,
        NF, 0, NF, 0, 0, NF, 0, NF, 0, 0,
        bias_p);

    // Wr' = W_r @ G^T in f32 (permuted rows), then hi/lo f16 split into Wcat cols 0..1023
    mfma_nt<128, 128, 2, 2, false, false><<<dim3(MSUP / 128, G4 / 128), blk, 0, stream>>>(
        Wr32, MSUP,
        Wih_h + FEAT, 2 * FEAT, G_h, FEAT, FEAT,
        NF, 0, NF, 0, 0, NF, 0, NF, 0, 0,
        nullptr);
    split_wcat_kernel<<<(G4 * MSUP) / 1024, blk, 0, stream>>>(Wr32, Wcat);

    const f16* hcur = h0;
    for (int it = 0; it < NWAYS; ++it) {
        // aT[m][n] = G[m]·h[n] (transposed → contiguous row softmax)
        mfma_nt<64, 64, 2, 2, false, false><<<dim3(NB / 64, MSUP / 64), blk, 0, stream>>>(
            aT, NB,
            G_h, FEAT, hcur, FEAT, FEAT,
            NF, 0, NF, 0, 0, NF, 0, NF, 0, 0,
            nullptr);

        softmax_rows_kernel<<<MSUP, blk, 0, stream>>>(aT, aTh);
        transpose_f16_kernel<<<dim3(NB / 64, MSUP / 64), blk, 0, stream>>>(aTh, a_h, MSUP, NB);

        // gates = pre + [a|a|h] @ Wcat^T, fused LSTM cell epilogue (8-phase-class)
        f16* hnext = (it & 1) ? hB : hA;
        gates_8p<<<dim3(G4 / 256, NB / 256), 512, 131072, stream>>>(
            a_h, hcur, Wcat, pre_h, f, cbuf, hnext, h, it == 0, it == NWAYS - 1);
        hcur = hnext;
    }
}